// Round 1
// baseline (1390.129 us; speedup 1.0000x reference)
//
#include <hip/hip_runtime.h>
#include <hip/hip_bf16.h>
#include <math.h>

#define NUM_PM 254
#define NUM_VM 768
#define SEQQ   1024      // NUM_PM + NUM_VM + 2
#define NH     8
#define DD     256
#define DH     32
#define FF     1024
#define NB     8
#define MROWS  (NB*SEQQ) // 8192

__device__ __forceinline__ float gelu_tanh(float x){
    float x3 = x*x*x;
    float t = tanhf(0.7978845608028654f*(x + 0.044715f*x3));
    return 0.5f*x*(1.0f+t);
}

// ---------------------------------------------------------------- embed
__global__ void embed_kernel(const float* __restrict__ vm_states,
                             const float* __restrict__ num_step,
                             const float* __restrict__ pm_states,
                             const float* __restrict__ pm_W, const float* __restrict__ pm_b,
                             const float* __restrict__ vm_W, const float* __restrict__ vm_b,
                             float* __restrict__ x)
{
    int row = blockIdx.x;            // 0..8191
    int b = row >> 10, s = row & 1023;
    int d = threadIdx.x;             // 0..255
    __shared__ float in_s[16];
    float out;
    if (s == 0) {
        out = num_step[b];
    } else if (s == SEQQ-1) {
        out = -1.0f;
    } else if (s <= NUM_PM) {
        if (d < 16) in_s[d] = pm_states[(size_t)(b*NUM_PM + (s-1))*16 + d];
        __syncthreads();
        float acc = pm_b[d];
        #pragma unroll
        for (int k=0;k<16;k++) acc = fmaf(in_s[k], pm_W[k*DD + d], acc);
        out = acc;
    } else {
        if (d < 16) in_s[d] = vm_states[(size_t)(b*NUM_VM + (s-1-NUM_PM))*16 + d];
        __syncthreads();
        float acc = vm_b[d];
        #pragma unroll
        for (int k=0;k<16;k++) acc = fmaf(in_s[k], vm_W[k*DD + d], acc);
        out = acc;
    }
    x[(size_t)row*DD + d] = out;
}

// ---------------------------------------------------------------- layernorm
__global__ void ln_kernel(const float* __restrict__ x, const float* __restrict__ g,
                          const float* __restrict__ bta, float* __restrict__ out)
{
    __shared__ float p1[4], p2[4];
    __shared__ float mean_s, rstd_s;
    int row = blockIdx.x; int tid = threadIdx.x;
    float v = x[(size_t)row*DD + tid];
    float s1 = v, s2 = v*v;
    #pragma unroll
    for (int off=32; off; off>>=1){ s1 += __shfl_down(s1,off); s2 += __shfl_down(s2,off); }
    int wave = tid >> 6, lane = tid & 63;
    if (lane == 0){ p1[wave]=s1; p2[wave]=s2; }
    __syncthreads();
    if (tid == 0){
        float a  = p1[0]+p1[1]+p1[2]+p1[3];
        float b2 = p2[0]+p2[1]+p2[2]+p2[3];
        float m = a * (1.0f/DD);
        float var = b2*(1.0f/DD) - m*m;
        mean_s = m; rstd_s = rsqrtf(var + 1e-5f);
    }
    __syncthreads();
    out[(size_t)row*DD + tid] = (v - mean_s)*rstd_s*g[tid] + bta[tid];
}

// ---------------------------------------------------------------- GEMM  C[M,N] = A[M,K]@W[K,N]+bias (+res|+gelu)
// EPI: 0=bias, 1=bias+residual, 2=bias+gelu
template<int EPI>
__launch_bounds__(256)
__global__ void gemm_kernel(const float* __restrict__ A, const float* __restrict__ W,
                            const float* __restrict__ bias, const float* __restrict__ res,
                            float* __restrict__ C, int N, int K)
{
    __shared__ float As[16][64];
    __shared__ float Bs[16][64];
    int tid = threadIdx.x;
    int tr = tid >> 4, tc = tid & 15;
    int row0 = blockIdx.y*64, col0 = blockIdx.x*64;
    float acc[4][4] = {};
    int ar = tid >> 2, ac = (tid&3)*4;   // A load: 64 rows x 16 cols
    int br = tid >> 4, bc = (tid&15)*4;  // B load: 16 rows x 64 cols
    for (int k0=0; k0<K; k0+=16){
        float4 av = *(const float4*)&A[(size_t)(row0+ar)*K + k0 + ac];
        float4 bv = *(const float4*)&W[(size_t)(k0+br)*N + col0 + bc];
        As[ac+0][ar]=av.x; As[ac+1][ar]=av.y; As[ac+2][ar]=av.z; As[ac+3][ar]=av.w;
        *(float4*)&Bs[br][bc] = bv;
        __syncthreads();
        #pragma unroll
        for (int kk=0;kk<16;kk++){
            float4 a4 = *(const float4*)&As[kk][tr*4];
            float4 b4 = *(const float4*)&Bs[kk][tc*4];
            float a_[4]={a4.x,a4.y,a4.z,a4.w};
            float b_[4]={b4.x,b4.y,b4.z,b4.w};
            #pragma unroll
            for (int i=0;i<4;i++)
                #pragma unroll
                for (int j=0;j<4;j++)
                    acc[i][j] = fmaf(a_[i], b_[j], acc[i][j]);
        }
        __syncthreads();
    }
    #pragma unroll
    for (int i=0;i<4;i++){
        int r = row0 + tr*4 + i;
        size_t base = (size_t)r*N + col0 + tc*4;
        float vj[4];
        #pragma unroll
        for (int j=0;j<4;j++) vj[j] = acc[i][j] + bias[col0 + tc*4 + j];
        if (EPI==1){
            float4 rv = *(const float4*)&res[base];
            vj[0]+=rv.x; vj[1]+=rv.y; vj[2]+=rv.z; vj[3]+=rv.w;
        }
        if (EPI==2){
            #pragma unroll
            for (int j=0;j<4;j++) vj[j] = gelu_tanh(vj[j]);
        }
        float4 outv = {vj[0],vj[1],vj[2],vj[3]};
        *(float4*)&C[base] = outv;
    }
}

// ---------------------------------------------------------------- attention (group-sparse flash)
__launch_bounds__(256)
__global__ void attn_kernel(const float* __restrict__ qkv, const int* __restrict__ rel,
                            const unsigned char* __restrict__ mask, float* __restrict__ o)
{
    // grid: (SEQQ/256, NH, NB); one thread per query row
    int b = blockIdx.z, h = blockIdx.y, q0 = blockIdx.x*256;
    int tid = threadIdx.x;
    int s = q0 + tid;
    int qc;
    if (s==0) qc = -1; else if (s==SEQQ-1) qc = -2; else qc = rel[b*(SEQQ-2) + s-1];
    const float scale = 0.17677669529663687f; // 1/sqrt(32)
    float q_reg[32];
    const float* qrow = qkv + ((size_t)(b*SEQQ+s))*768 + h*32;
    #pragma unroll
    for (int d=0; d<32; d++) q_reg[d] = qrow[d]*scale;
    float m = -1e30f, l = 0.f, acc[32];
    #pragma unroll
    for (int d=0; d<32; d++) acc[d]=0.f;

    __shared__ float Ks[64][36];
    __shared__ float Vs[64][36];
    __shared__ int   kcs[64];

    for (int k0=0;k0<SEQQ;k0+=64){
        __syncthreads();   // protect prior-iter reads
        #pragma unroll
        for (int rep=0; rep<2; rep++){
            int fid = tid + rep*256;              // 512 float4 per K tile
            int j = fid >> 3, d4 = (fid&7)*4;
            const float* kp = qkv + ((size_t)(b*SEQQ + k0 + j))*768 + 256 + h*32 + d4;
            *(float4*)&Ks[j][d4] = *(const float4*)kp;
            *(float4*)&Vs[j][d4] = *(const float4*)(kp + 256);
        }
        if (tid < 64){
            int k = k0 + tid;
            int kc;
            if (k==0) kc=-1;
            else if (k==SEQQ-1) kc=-2;
            else {
                kc = rel[b*(SEQQ-2)+k-1];
                if (k >= 1+NUM_PM && mask[b*NUM_VM + (k-1-NUM_PM)]) kc = -3;
            }
            kcs[tid]=kc;
        }
        __syncthreads();
        for (int j=0;j<64;j++){
            if (kcs[j] != qc) continue;   // group-sparse skip (exact: exp underflow)
            float sc = 0.f;
            #pragma unroll
            for (int d=0;d<32;d++) sc = fmaf(q_reg[d], Ks[j][d], sc);
            float mn = fmaxf(m, sc);
            float corr = __expf(m - mn);
            float p = __expf(sc - mn);
            l = l*corr + p;
            #pragma unroll
            for (int d=0;d<32;d++) acc[d] = fmaf(p, Vs[j][d], acc[d]*corr);
            m = mn;
        }
    }
    float inv = 1.0f/l;
    float* orow = o + ((size_t)(b*SEQQ+s))*DD + h*32;
    #pragma unroll
    for (int d=0;d<32;d++) orow[d] = acc[d]*inv;
}

// ---------------------------------------------------------------- head
__global__ void out_kernel(const float* __restrict__ x,
                           const float* __restrict__ out_W, const float* __restrict__ out_b,
                           const float* __restrict__ crit_W, const float* __restrict__ crit_b,
                           float* __restrict__ out)
{
    int gidx = blockIdx.x*4 + (threadIdx.x>>6);
    int lane = threadIdx.x & 63;
    if (gidx >= NB*769) return;
    int b = gidx / 769, j = gidx % 769;
    int srow; const float* Wp; float bb;
    if (j < 768){ srow = b*SEQQ + 1 + NUM_PM + j; Wp = out_W; bb = out_b[0]; }
    else        { srow = b*SEQQ + SEQQ-1;         Wp = crit_W; bb = crit_b[0]; }
    const float* xr = x + (size_t)srow*DD;
    float4 xv = *(const float4*)&xr[lane*4];
    float4 wv = *(const float4*)&Wp[lane*4];
    float sdot = xv.x*wv.x + xv.y*wv.y + xv.z*wv.z + xv.w*wv.w;
    #pragma unroll
    for (int off=32; off; off>>=1) sdot += __shfl_down(sdot, off);
    if (lane==0) out[gidx] = sdot + bb;
}

// ---------------------------------------------------------------- launch
extern "C" void kernel_launch(void* const* d_in, const int* in_sizes, int n_in,
                              void* d_out, int out_size, void* d_ws, size_t ws_size,
                              hipStream_t stream)
{
    const float* vm_states = (const float*)d_in[0];
    const float* num_step  = (const float*)d_in[1];
    const float* pm_states = (const float*)d_in[2];
    const int*   rel       = (const int*)d_in[3];
    const unsigned char* mask = (const unsigned char*)d_in[4];
    const float* pm_W = (const float*)d_in[5];
    const float* pm_b = (const float*)d_in[6];
    const float* vm_W = (const float*)d_in[7];
    const float* vm_b = (const float*)d_in[8];
    const float* Wqkv = (const float*)d_in[9];
    const float* bqkv = (const float*)d_in[10];
    const float* Wo   = (const float*)d_in[11];
    const float* bo   = (const float*)d_in[12];
    const float* ln1g = (const float*)d_in[13];
    const float* ln1b = (const float*)d_in[14];
    const float* ln2g = (const float*)d_in[15];
    const float* ln2b = (const float*)d_in[16];
    const float* W1   = (const float*)d_in[17];
    const float* b1   = (const float*)d_in[18];
    const float* W2   = (const float*)d_in[19];
    const float* b2   = (const float*)d_in[20];
    const float* out_W = (const float*)d_in[21];
    const float* out_b = (const float*)d_in[22];
    const float* crit_W = (const float*)d_in[23];
    const float* crit_b = (const float*)d_in[24];

    char* ws = (char*)d_ws;
    float* x    = (float*)(ws);                              // 8 MiB  (8192x256)
    float* hbuf = (float*)(ws + (size_t) 8*1024*1024);       // 8 MiB  (8192x256)
    float* big  = (float*)(ws + (size_t)16*1024*1024);       // 32 MiB (8192x1024; qkv then ff1)
    float* aout = (float*)(ws + (size_t)48*1024*1024);       // 8 MiB  (8192x256)

    embed_kernel<<<MROWS, 256, 0, stream>>>(vm_states, num_step, pm_states,
                                            pm_W, pm_b, vm_W, vm_b, x);
    for (int i=0;i<3;i++){
        ln_kernel<<<MROWS,256,0,stream>>>(x, ln1g + i*DD, ln1b + i*DD, hbuf);
        gemm_kernel<0><<<dim3(768/64, MROWS/64),256,0,stream>>>(
            hbuf, Wqkv + (size_t)i*DD*768, bqkv + i*768, nullptr, big, 768, DD);
        attn_kernel<<<dim3(SEQQ/256, NH, NB),256,0,stream>>>(big, rel, mask, aout);
        gemm_kernel<1><<<dim3(DD/64, MROWS/64),256,0,stream>>>(
            aout, Wo + (size_t)i*DD*DD, bo + i*DD, x, x, DD, DD);
        ln_kernel<<<MROWS,256,0,stream>>>(x, ln2g + i*DD, ln2b + i*DD, hbuf);
        gemm_kernel<2><<<dim3(FF/64, MROWS/64),256,0,stream>>>(
            hbuf, W1 + (size_t)i*DD*FF, b1 + i*FF, nullptr, big, FF, DD);
        gemm_kernel<1><<<dim3(DD/64, MROWS/64),256,0,stream>>>(
            big, W2 + (size_t)i*FF*DD, b2 + i*DD, x, x, DD, FF);
    }
    out_kernel<<<(NB*769+3)/4, 256, 0, stream>>>(x, out_W, out_b, crit_W, crit_b, (float*)d_out);
}

// Round 2
// 841.467 us; speedup vs baseline: 1.6520x; 1.6520x over previous
//
#include <hip/hip_runtime.h>
#include <hip/hip_bf16.h>
#include <math.h>

#define NUM_PM 254
#define NUM_VM 768
#define SEQQ   1024      // NUM_PM + NUM_VM + 2
#define NH     8
#define DD     256
#define DH     32
#define FF     1024
#define NB     8
#define MROWS  (NB*SEQQ) // 8192

__device__ __forceinline__ float gelu_tanh(float x){
    float x3 = x*x*x;
    float t = tanhf(0.7978845608028654f*(x + 0.044715f*x3));
    return 0.5f*x*(1.0f+t);
}

// ---------------------------------------------------------------- embed
__global__ void embed_kernel(const float* __restrict__ vm_states,
                             const float* __restrict__ num_step,
                             const float* __restrict__ pm_states,
                             const float* __restrict__ pm_W, const float* __restrict__ pm_b,
                             const float* __restrict__ vm_W, const float* __restrict__ vm_b,
                             float* __restrict__ x)
{
    int row = blockIdx.x;            // 0..8191
    int b = row >> 10, s = row & 1023;
    int d = threadIdx.x;             // 0..255
    __shared__ float in_s[16];
    float out;
    if (s == 0) {
        out = num_step[b];
    } else if (s == SEQQ-1) {
        out = -1.0f;
    } else if (s <= NUM_PM) {
        if (d < 16) in_s[d] = pm_states[(size_t)(b*NUM_PM + (s-1))*16 + d];
        __syncthreads();
        float acc = pm_b[d];
        #pragma unroll
        for (int k=0;k<16;k++) acc = fmaf(in_s[k], pm_W[k*DD + d], acc);
        out = acc;
    } else {
        if (d < 16) in_s[d] = vm_states[(size_t)(b*NUM_VM + (s-1-NUM_PM))*16 + d];
        __syncthreads();
        float acc = vm_b[d];
        #pragma unroll
        for (int k=0;k<16;k++) acc = fmaf(in_s[k], vm_W[k*DD + d], acc);
        out = acc;
    }
    x[(size_t)row*DD + d] = out;
}

// ---------------------------------------------------------------- layernorm
__global__ void ln_kernel(const float* __restrict__ x, const float* __restrict__ g,
                          const float* __restrict__ bta, float* __restrict__ out)
{
    __shared__ float p1[4], p2[4];
    __shared__ float mean_s, rstd_s;
    int row = blockIdx.x; int tid = threadIdx.x;
    float v = x[(size_t)row*DD + tid];
    float s1 = v, s2 = v*v;
    #pragma unroll
    for (int off=32; off; off>>=1){ s1 += __shfl_down(s1,off); s2 += __shfl_down(s2,off); }
    int wave = tid >> 6, lane = tid & 63;
    if (lane == 0){ p1[wave]=s1; p2[wave]=s2; }
    __syncthreads();
    if (tid == 0){
        float a  = p1[0]+p1[1]+p1[2]+p1[3];
        float b2 = p2[0]+p2[1]+p2[2]+p2[3];
        float m = a * (1.0f/DD);
        float var = b2*(1.0f/DD) - m*m;
        mean_s = m; rstd_s = rsqrtf(var + 1e-5f);
    }
    __syncthreads();
    out[(size_t)row*DD + tid] = (v - mean_s)*rstd_s*g[tid] + bta[tid];
}

// ---------------------------------------------------------------- GEMM  C[M,N] = A[M,K]@W[K,N]+bias (+res|+gelu)
// EPI: 0=bias, 1=bias+residual, 2=bias+gelu
template<int EPI>
__launch_bounds__(256)
__global__ void gemm_kernel(const float* __restrict__ A, const float* __restrict__ W,
                            const float* __restrict__ bias, const float* __restrict__ res,
                            float* __restrict__ C, int N, int K)
{
    __shared__ float As[16][64];
    __shared__ float Bs[16][64];
    int tid = threadIdx.x;
    int tr = tid >> 4, tc = tid & 15;
    int row0 = blockIdx.y*64, col0 = blockIdx.x*64;
    float acc[4][4] = {};
    int ar = tid >> 2, ac = (tid&3)*4;   // A load: 64 rows x 16 cols
    int br = tid >> 4, bc = (tid&15)*4;  // B load: 16 rows x 64 cols
    for (int k0=0; k0<K; k0+=16){
        float4 av = *(const float4*)&A[(size_t)(row0+ar)*K + k0 + ac];
        float4 bv = *(const float4*)&W[(size_t)(k0+br)*N + col0 + bc];
        As[ac+0][ar]=av.x; As[ac+1][ar]=av.y; As[ac+2][ar]=av.z; As[ac+3][ar]=av.w;
        *(float4*)&Bs[br][bc] = bv;
        __syncthreads();
        #pragma unroll
        for (int kk=0;kk<16;kk++){
            float4 a4 = *(const float4*)&As[kk][tr*4];
            float4 b4 = *(const float4*)&Bs[kk][tc*4];
            float a_[4]={a4.x,a4.y,a4.z,a4.w};
            float b_[4]={b4.x,b4.y,b4.z,b4.w};
            #pragma unroll
            for (int i=0;i<4;i++)
                #pragma unroll
                for (int j=0;j<4;j++)
                    acc[i][j] = fmaf(a_[i], b_[j], acc[i][j]);
        }
        __syncthreads();
    }
    #pragma unroll
    for (int i=0;i<4;i++){
        int r = row0 + tr*4 + i;
        size_t base = (size_t)r*N + col0 + tc*4;
        float vj[4];
        #pragma unroll
        for (int j=0;j<4;j++) vj[j] = acc[i][j] + bias[col0 + tc*4 + j];
        if (EPI==1){
            float4 rv = *(const float4*)&res[base];
            vj[0]+=rv.x; vj[1]+=rv.y; vj[2]+=rv.z; vj[3]+=rv.w;
        }
        if (EPI==2){
            #pragma unroll
            for (int j=0;j<4;j++) vj[j] = gelu_tanh(vj[j]);
        }
        float4 outv = {vj[0],vj[1],vj[2],vj[3]};
        *(float4*)&C[base] = outv;
    }
}

// ---------------------------------------------------------------- group build (counting sort by (b, code))
// counts/offs: [NB][256] ints; mypos: [NB][SEQQ]; members: [NB][SEQQ]
__global__ void group_count_kernel(const int* __restrict__ rel, const unsigned char* __restrict__ mask,
                                   int* __restrict__ counts, int* __restrict__ mypos)
{
    int idx = blockIdx.x*256 + threadIdx.x;
    if (idx >= NB*SEQQ) return;
    int b = idx >> 10, s = idx & 1023;
    if (s == 0 || s == SEQQ-1) return;
    if (s >= 1+NUM_PM && mask[b*NUM_VM + (s-1-NUM_PM)]) return;  // masked key: excluded
    int c = rel[b*(SEQQ-2) + s-1];
    int p = atomicAdd(&counts[b*256 + c], 1);
    mypos[idx] = p;
}

__global__ void group_scan_kernel(const int* __restrict__ counts, int* __restrict__ offs)
{
    int b = threadIdx.x;   // 8 threads
    if (b >= NB) return;
    int run = 0;
    for (int c = 0; c < 256; c++){
        offs[b*256 + c] = run;
        run += counts[b*256 + c];
    }
}

__global__ void group_scatter_kernel(const int* __restrict__ rel, const unsigned char* __restrict__ mask,
                                     const int* __restrict__ offs, const int* __restrict__ mypos,
                                     int* __restrict__ members)
{
    int idx = blockIdx.x*256 + threadIdx.x;
    if (idx >= NB*SEQQ) return;
    int b = idx >> 10, s = idx & 1023;
    if (s == 0 || s == SEQQ-1) return;
    if (s >= 1+NUM_PM && mask[b*NUM_VM + (s-1-NUM_PM)]) return;
    int c = rel[b*(SEQQ-2) + s-1];
    members[b*SEQQ + offs[b*256 + c] + mypos[idx]] = s;
}

// ---------------------------------------------------------------- attention (gathered group-sparse)
// one wave per (b, q); lane = h*8 + i holds dims [lane*4, lane*4+4) of the 256-dim row
__launch_bounds__(256)
__global__ void attn_kernel(const float* __restrict__ qkv, const int* __restrict__ rel,
                            const int* __restrict__ counts, const int* __restrict__ offs,
                            const int* __restrict__ members, float* __restrict__ o)
{
    int gq = blockIdx.x*4 + (threadIdx.x >> 6);     // 0..8191
    int lane = threadIdx.x & 63;
    int b = gq >> 10, s = gq & 1023;
    const float scale = 0.17677669529663687f;       // 1/sqrt(32)

    const float* base = qkv + (size_t)(b*SEQQ + s)*768;
    float4 q4 = *(const float4*)(base + lane*4);
    q4.x *= scale; q4.y *= scale; q4.z *= scale; q4.w *= scale;

    int cnt; const int* mlist = nullptr;
    if (s == 0 || s == SEQQ-1) { cnt = 1; }
    else {
        int c = rel[b*(SEQQ-2) + s-1];
        cnt   = counts[b*256 + c];
        mlist = members + b*SEQQ + offs[b*256 + c];
    }

    float m_run = -1e30f, l_run = 0.f;
    float4 acc = {0.f,0.f,0.f,0.f};
    for (int j = 0; j < cnt; j++){
        int mi = mlist ? mlist[j] : s;
        const float* kb = qkv + (size_t)(b*SEQQ + mi)*768 + 256 + lane*4;
        float4 k4 = *(const float4*)kb;
        float4 v4 = *(const float4*)(kb + 256);
        float sc = q4.x*k4.x + q4.y*k4.y + q4.z*k4.z + q4.w*k4.w;
        sc += __shfl_xor(sc, 1);
        sc += __shfl_xor(sc, 2);
        sc += __shfl_xor(sc, 4);                    // full head-dot in all 8 lanes of the head
        float mn = fmaxf(m_run, sc);
        float corr = __expf(m_run - mn);
        float p = __expf(sc - mn);
        l_run = l_run*corr + p;
        acc.x = acc.x*corr + p*v4.x;
        acc.y = acc.y*corr + p*v4.y;
        acc.z = acc.z*corr + p*v4.z;
        acc.w = acc.w*corr + p*v4.w;
        m_run = mn;
    }
    float inv = (l_run > 0.f) ? 1.0f/l_run : 0.f;
    float* orow = o + (size_t)(b*SEQQ + s)*DD + lane*4;
    float4 outv = {acc.x*inv, acc.y*inv, acc.z*inv, acc.w*inv};
    *(float4*)orow = outv;
}

// ---------------------------------------------------------------- head
__global__ void out_kernel(const float* __restrict__ x,
                           const float* __restrict__ out_W, const float* __restrict__ out_b,
                           const float* __restrict__ crit_W, const float* __restrict__ crit_b,
                           float* __restrict__ out)
{
    int gidx = blockIdx.x*4 + (threadIdx.x>>6);
    int lane = threadIdx.x & 63;
    if (gidx >= NB*769) return;
    int b = gidx / 769, j = gidx % 769;
    int srow; const float* Wp; float bb;
    if (j < 768){ srow = b*SEQQ + 1 + NUM_PM + j; Wp = out_W; bb = out_b[0]; }
    else        { srow = b*SEQQ + SEQQ-1;         Wp = crit_W; bb = crit_b[0]; }
    const float* xr = x + (size_t)srow*DD;
    float4 xv = *(const float4*)&xr[lane*4];
    float4 wv = *(const float4*)&Wp[lane*4];
    float sdot = xv.x*wv.x + xv.y*wv.y + xv.z*wv.z + xv.w*wv.w;
    #pragma unroll
    for (int off=32; off; off>>=1) sdot += __shfl_down(sdot, off);
    if (lane==0) out[gidx] = sdot + bb;
}

// ---------------------------------------------------------------- launch
extern "C" void kernel_launch(void* const* d_in, const int* in_sizes, int n_in,
                              void* d_out, int out_size, void* d_ws, size_t ws_size,
                              hipStream_t stream)
{
    const float* vm_states = (const float*)d_in[0];
    const float* num_step  = (const float*)d_in[1];
    const float* pm_states = (const float*)d_in[2];
    const int*   rel       = (const int*)d_in[3];
    const unsigned char* mask = (const unsigned char*)d_in[4];
    const float* pm_W = (const float*)d_in[5];
    const float* pm_b = (const float*)d_in[6];
    const float* vm_W = (const float*)d_in[7];
    const float* vm_b = (const float*)d_in[8];
    const float* Wqkv = (const float*)d_in[9];
    const float* bqkv = (const float*)d_in[10];
    const float* Wo   = (const float*)d_in[11];
    const float* bo   = (const float*)d_in[12];
    const float* ln1g = (const float*)d_in[13];
    const float* ln1b = (const float*)d_in[14];
    const float* ln2g = (const float*)d_in[15];
    const float* ln2b = (const float*)d_in[16];
    const float* W1   = (const float*)d_in[17];
    const float* b1   = (const float*)d_in[18];
    const float* W2   = (const float*)d_in[19];
    const float* b2   = (const float*)d_in[20];
    const float* out_W = (const float*)d_in[21];
    const float* out_b = (const float*)d_in[22];
    const float* crit_W = (const float*)d_in[23];
    const float* crit_b = (const float*)d_in[24];

    char* ws = (char*)d_ws;
    float* x    = (float*)(ws);                              // 8 MiB  (8192x256)
    float* hbuf = (float*)(ws + (size_t) 8*1024*1024);       // 8 MiB  (8192x256)
    float* big  = (float*)(ws + (size_t)16*1024*1024);       // 32 MiB (8192x1024; qkv then ff1)
    float* aout = (float*)(ws + (size_t)48*1024*1024);       // 8 MiB  (8192x256)
    int*   counts  = (int*)(ws + (size_t)56*1024*1024);      // 8x256 ints
    int*   offs    = counts + NB*256;                        // 8x256 ints
    int*   mypos   = offs   + NB*256;                        // 8x1024 ints
    int*   members = mypos  + NB*SEQQ;                       // 8x1024 ints

    hipMemsetAsync(counts, 0, NB*256*sizeof(int), stream);
    group_count_kernel<<<MROWS/256, 256, 0, stream>>>(rel, mask, counts, mypos);
    group_scan_kernel<<<1, 64, 0, stream>>>(counts, offs);
    group_scatter_kernel<<<MROWS/256, 256, 0, stream>>>(rel, mask, offs, mypos, members);

    embed_kernel<<<MROWS, 256, 0, stream>>>(vm_states, num_step, pm_states,
                                            pm_W, pm_b, vm_W, vm_b, x);
    for (int i=0;i<3;i++){
        ln_kernel<<<MROWS,256,0,stream>>>(x, ln1g + i*DD, ln1b + i*DD, hbuf);
        gemm_kernel<0><<<dim3(768/64, MROWS/64),256,0,stream>>>(
            hbuf, Wqkv + (size_t)i*DD*768, bqkv + i*768, nullptr, big, 768, DD);
        attn_kernel<<<MROWS/4, 256, 0, stream>>>(big, rel, counts, offs, members, aout);
        gemm_kernel<1><<<dim3(DD/64, MROWS/64),256,0,stream>>>(
            aout, Wo + (size_t)i*DD*DD, bo + i*DD, x, x, DD, DD);
        ln_kernel<<<MROWS,256,0,stream>>>(x, ln2g + i*DD, ln2b + i*DD, hbuf);
        gemm_kernel<2><<<dim3(FF/64, MROWS/64),256,0,stream>>>(
            hbuf, W1 + (size_t)i*DD*FF, b1 + i*FF, nullptr, big, FF, DD);
        gemm_kernel<1><<<dim3(DD/64, MROWS/64),256,0,stream>>>(
            big, W2 + (size_t)i*FF*DD, b2 + i*DD, x, x, DD, FF);
    }
    out_kernel<<<(NB*769+3)/4, 256, 0, stream>>>(x, out_W, out_b, crit_W, crit_b, (float*)d_out);
}

// Round 3
// 421.974 us; speedup vs baseline: 3.2943x; 1.9941x over previous
//
#include <hip/hip_runtime.h>
#include <hip/hip_bf16.h>
#include <math.h>

#define NUM_PM 254
#define NUM_VM 768
#define SEQQ   1024      // NUM_PM + NUM_VM + 2
#define NH     8
#define DD     256
#define DH     32
#define FF     1024
#define NB     8
#define MROWS  (NB*SEQQ) // 8192

typedef unsigned short u16;
typedef __attribute__((ext_vector_type(8))) short bf16x8;
typedef __attribute__((ext_vector_type(4))) float f32x4;

__device__ __forceinline__ float bf2f(u16 u){
    union { float f; unsigned int i; } c; c.i = ((unsigned int)u) << 16; return c.f;
}
__device__ __forceinline__ u16 f2bf(float f){
    union { float f; unsigned int u; } c; c.f = f;
    unsigned int r = c.u + 0x7FFFu + ((c.u >> 16) & 1u);   // RNE
    return (u16)(r >> 16);
}
__device__ __forceinline__ float gelu_tanh(float x){
    float x3 = x*x*x;
    float t = tanhf(0.7978845608028654f*(x + 0.044715f*x3));
    return 0.5f*x*(1.0f+t);
}

#define GLOAD16(gp, lp) __builtin_amdgcn_global_load_lds( \
    (const __attribute__((address_space(1))) void*)(gp), \
    (__attribute__((address_space(3))) void*)(lp), 16, 0, 0)

// ---------------------------------------------------------------- embed (x stays f32)
__global__ void embed_kernel(const float* __restrict__ vm_states,
                             const float* __restrict__ num_step,
                             const float* __restrict__ pm_states,
                             const float* __restrict__ pm_W, const float* __restrict__ pm_b,
                             const float* __restrict__ vm_W, const float* __restrict__ vm_b,
                             float* __restrict__ x)
{
    int row = blockIdx.x;
    int b = row >> 10, s = row & 1023;
    int d = threadIdx.x;
    __shared__ float in_s[16];
    float out;
    if (s == 0) {
        out = num_step[b];
    } else if (s == SEQQ-1) {
        out = -1.0f;
    } else if (s <= NUM_PM) {
        if (d < 16) in_s[d] = pm_states[(size_t)(b*NUM_PM + (s-1))*16 + d];
        __syncthreads();
        float acc = pm_b[d];
        #pragma unroll
        for (int k=0;k<16;k++) acc = fmaf(in_s[k], pm_W[k*DD + d], acc);
        out = acc;
    } else {
        if (d < 16) in_s[d] = vm_states[(size_t)(b*NUM_VM + (s-1-NUM_PM))*16 + d];
        __syncthreads();
        float acc = vm_b[d];
        #pragma unroll
        for (int k=0;k<16;k++) acc = fmaf(in_s[k], vm_W[k*DD + d], acc);
        out = acc;
    }
    x[(size_t)row*DD + d] = out;
}

// ---------------------------------------------------------------- layernorm: f32 in -> bf16 out
__global__ void ln_kernel(const float* __restrict__ x, const float* __restrict__ g,
                          const float* __restrict__ bta, u16* __restrict__ out)
{
    __shared__ float p1[4], p2[4];
    __shared__ float mean_s, rstd_s;
    int row = blockIdx.x; int tid = threadIdx.x;
    float v = x[(size_t)row*DD + tid];
    float s1 = v, s2 = v*v;
    #pragma unroll
    for (int off=32; off; off>>=1){ s1 += __shfl_down(s1,off); s2 += __shfl_down(s2,off); }
    int wave = tid >> 6, lane = tid & 63;
    if (lane == 0){ p1[wave]=s1; p2[wave]=s2; }
    __syncthreads();
    if (tid == 0){
        float a  = p1[0]+p1[1]+p1[2]+p1[3];
        float b2 = p2[0]+p2[1]+p2[2]+p2[3];
        float m = a * (1.0f/DD);
        float var = b2*(1.0f/DD) - m*m;
        mean_s = m; rstd_s = rsqrtf(var + 1e-5f);
    }
    __syncthreads();
    out[(size_t)row*DD + tid] = f2bf((v - mean_s)*rstd_s*g[tid] + bta[tid]);
}

// ---------------------------------------------------------------- transpose-cast: in [K][N] f32 -> out [N][K] bf16, per layer (blockIdx.z)
__global__ void tcast_kernel(const float* __restrict__ in, u16* __restrict__ out, int K, int N)
{
    __shared__ float t[32][33];
    size_t lofs = (size_t)blockIdx.z * K * N;
    int n0 = blockIdx.x*32, k0 = blockIdx.y*32;
    int tx = threadIdx.x & 31, ty = threadIdx.x >> 5;   // ty 0..7
    #pragma unroll
    for (int i=0;i<4;i++)
        t[ty + i*8][tx] = in[lofs + (size_t)(k0 + ty + i*8)*N + n0 + tx];
    __syncthreads();
    #pragma unroll
    for (int i=0;i<4;i++)
        out[lofs + (size_t)(n0 + ty + i*8)*K + k0 + tx] = f2bf(t[tx][ty + i*8]);
}

// ---------------------------------------------------------------- MFMA GEMM: C[M,N] = A[M,K] @ Bt[N,K]^T + bias
// A, Bt bf16; EPI: 0 = bias -> bf16 C; 1 = bias + res -> f32 C; 2 = bias + gelu -> bf16 C
template<int EPI>
__launch_bounds__(256)
__global__ void mgemm_kernel(const u16* __restrict__ A, const u16* __restrict__ Bt,
                             const float* __restrict__ bias, const float* __restrict__ res,
                             void* __restrict__ C, int N, int K)
{
    __shared__ u16 As[128][32];
    __shared__ u16 Bs[128][32];
    int tid = threadIdx.x;
    int wid = tid >> 6, lane = tid & 63;
    int wr = wid >> 1, wc = wid & 1;            // 2x2 wave grid, wave tile 64x64
    int row0 = blockIdx.y*128, col0 = blockIdx.x*128;
    int l15 = lane & 15, lh = lane >> 4;        // lh: 0..3

    // staging geometry: wave w, call c stages 16 rows at (w*32 + c*16); lane l -> row += l>>2, k-ofs (l&3)*8
    int srow = wid*32 + (lane>>2);
    int skof = (lane&3)*8;
    const u16* Ag = A  + (size_t)(row0 + srow)*K + skof;
    const u16* Bg = Bt + (size_t)(col0 + srow)*K + skof;
    u16* AsL0 = &As[wid*32][0];      u16* AsL1 = &As[wid*32+16][0];
    u16* BsL0 = &Bs[wid*32][0];      u16* BsL1 = &Bs[wid*32+16][0];

    f32x4 acc[4][4] = {};

    int nk = K >> 5;
    for (int kt = 0; kt < nk; kt++){
        int k0 = kt*32;
        __syncthreads();                         // protect previous iter's LDS reads
        GLOAD16(Ag + k0,            AsL0);
        GLOAD16(Ag + k0 + 16*K,     AsL1);
        GLOAD16(Bg + k0,            BsL0);
        GLOAD16(Bg + k0 + 16*K,     BsL1);
        __syncthreads();                         // drains vmcnt before LDS reads
        bf16x8 af[4], bfv[4];
        #pragma unroll
        for (int f=0; f<4; f++){
            af[f]  = *(const bf16x8*)&As[wr*64 + f*16 + l15][lh*8];
            bfv[f] = *(const bf16x8*)&Bs[wc*64 + f*16 + l15][lh*8];
        }
        #pragma unroll
        for (int i=0;i<4;i++)
            #pragma unroll
            for (int j=0;j<4;j++)
                acc[i][j] = __builtin_amdgcn_mfma_f32_16x16x32_bf16(af[i], bfv[j], acc[i][j], 0,0,0);
    }

    #pragma unroll
    for (int i=0;i<4;i++){
        #pragma unroll
        for (int j=0;j<4;j++){
            int col = col0 + wc*64 + j*16 + l15;
            float bb = bias[col];
            #pragma unroll
            for (int r=0;r<4;r++){
                int row = row0 + wr*64 + i*16 + lh*4 + r;
                size_t idx = (size_t)row*N + col;
                float v = acc[i][j][r] + bb;
                if (EPI==1)      ((float*)C)[idx] = v + res[idx];
                else if (EPI==0) ((u16*)C)[idx]   = f2bf(v);
                else             ((u16*)C)[idx]   = f2bf(gelu_tanh(v));
            }
        }
    }
}

// ---------------------------------------------------------------- group build (counting sort by (b, code))
__global__ void group_count_kernel(const int* __restrict__ rel, const unsigned char* __restrict__ mask,
                                   int* __restrict__ counts, int* __restrict__ mypos)
{
    int idx = blockIdx.x*256 + threadIdx.x;
    if (idx >= NB*SEQQ) return;
    int b = idx >> 10, s = idx & 1023;
    if (s == 0 || s == SEQQ-1) return;
    if (s >= 1+NUM_PM && mask[b*NUM_VM + (s-1-NUM_PM)]) return;
    int c = rel[b*(SEQQ-2) + s-1];
    int p = atomicAdd(&counts[b*256 + c], 1);
    mypos[idx] = p;
}

__global__ void group_scan_kernel(const int* __restrict__ counts, int* __restrict__ offs)
{
    int b = threadIdx.x;
    if (b >= NB) return;
    int run = 0;
    for (int c = 0; c < 256; c++){
        offs[b*256 + c] = run;
        run += counts[b*256 + c];
    }
}

__global__ void group_scatter_kernel(const int* __restrict__ rel, const unsigned char* __restrict__ mask,
                                     const int* __restrict__ offs, const int* __restrict__ mypos,
                                     int* __restrict__ members)
{
    int idx = blockIdx.x*256 + threadIdx.x;
    if (idx >= NB*SEQQ) return;
    int b = idx >> 10, s = idx & 1023;
    if (s == 0 || s == SEQQ-1) return;
    if (s >= 1+NUM_PM && mask[b*NUM_VM + (s-1-NUM_PM)]) return;
    int c = rel[b*(SEQQ-2) + s-1];
    members[b*SEQQ + offs[b*256 + c] + mypos[idx]] = s;
}

// ---------------------------------------------------------------- attention (gathered group-sparse, bf16 qkv)
// one wave per (b, q); lane = h*8 + i holds dims [lane*4, lane*4+4)
__launch_bounds__(256)
__global__ void attn_kernel(const u16* __restrict__ qkv, const int* __restrict__ rel,
                            const int* __restrict__ counts, const int* __restrict__ offs,
                            const int* __restrict__ members, u16* __restrict__ o)
{
    int gq = blockIdx.x*4 + (threadIdx.x >> 6);
    int lane = threadIdx.x & 63;
    int b = gq >> 10, s = gq & 1023;
    const float scale = 0.17677669529663687f;       // 1/sqrt(32)

    const u16* base = qkv + (size_t)(b*SEQQ + s)*768 + lane*4;
    short4 q4i = *(const short4*)base;
    float qx = bf2f((u16)q4i.x)*scale, qy = bf2f((u16)q4i.y)*scale,
          qz = bf2f((u16)q4i.z)*scale, qw = bf2f((u16)q4i.w)*scale;

    int cnt; const int* mlist = nullptr;
    if (s == 0 || s == SEQQ-1) { cnt = 1; }
    else {
        int c = rel[b*(SEQQ-2) + s-1];
        cnt   = counts[b*256 + c];
        mlist = members + b*SEQQ + offs[b*256 + c];
    }

    float m_run = -1e30f, l_run = 0.f;
    float ax=0.f, ay=0.f, az=0.f, aw=0.f;
    for (int j = 0; j < cnt; j++){
        int mi = mlist ? mlist[j] : s;
        const u16* kb = qkv + (size_t)(b*SEQQ + mi)*768 + 256 + lane*4;
        short4 k4 = *(const short4*)kb;
        short4 v4 = *(const short4*)(kb + 256);
        float sc = qx*bf2f((u16)k4.x) + qy*bf2f((u16)k4.y)
                 + qz*bf2f((u16)k4.z) + qw*bf2f((u16)k4.w);
        sc += __shfl_xor(sc, 1);
        sc += __shfl_xor(sc, 2);
        sc += __shfl_xor(sc, 4);
        float mn = fmaxf(m_run, sc);
        float corr = __expf(m_run - mn);
        float p = __expf(sc - mn);
        l_run = l_run*corr + p;
        ax = ax*corr + p*bf2f((u16)v4.x);
        ay = ay*corr + p*bf2f((u16)v4.y);
        az = az*corr + p*bf2f((u16)v4.z);
        aw = aw*corr + p*bf2f((u16)v4.w);
        m_run = mn;
    }
    float inv = (l_run > 0.f) ? 1.0f/l_run : 0.f;
    u16* orow = o + (size_t)(b*SEQQ + s)*DD + lane*4;
    short4 outv;
    outv.x = (short)f2bf(ax*inv); outv.y = (short)f2bf(ay*inv);
    outv.z = (short)f2bf(az*inv); outv.w = (short)f2bf(aw*inv);
    *(short4*)orow = outv;
}

// ---------------------------------------------------------------- head (x f32)
__global__ void out_kernel(const float* __restrict__ x,
                           const float* __restrict__ out_W, const float* __restrict__ out_b,
                           const float* __restrict__ crit_W, const float* __restrict__ crit_b,
                           float* __restrict__ out)
{
    int gidx = blockIdx.x*4 + (threadIdx.x>>6);
    int lane = threadIdx.x & 63;
    if (gidx >= NB*769) return;
    int b = gidx / 769, j = gidx % 769;
    int srow; const float* Wp; float bb;
    if (j < 768){ srow = b*SEQQ + 1 + NUM_PM + j; Wp = out_W; bb = out_b[0]; }
    else        { srow = b*SEQQ + SEQQ-1;         Wp = crit_W; bb = crit_b[0]; }
    const float* xr = x + (size_t)srow*DD;
    float4 xv = *(const float4*)&xr[lane*4];
    float4 wv = *(const float4*)&Wp[lane*4];
    float sdot = xv.x*wv.x + xv.y*wv.y + xv.z*wv.z + xv.w*wv.w;
    #pragma unroll
    for (int off=32; off; off>>=1) sdot += __shfl_down(sdot, off);
    if (lane==0) out[gidx] = sdot + bb;
}

// ---------------------------------------------------------------- launch
extern "C" void kernel_launch(void* const* d_in, const int* in_sizes, int n_in,
                              void* d_out, int out_size, void* d_ws, size_t ws_size,
                              hipStream_t stream)
{
    const float* vm_states = (const float*)d_in[0];
    const float* num_step  = (const float*)d_in[1];
    const float* pm_states = (const float*)d_in[2];
    const int*   rel       = (const int*)d_in[3];
    const unsigned char* mask = (const unsigned char*)d_in[4];
    const float* pm_W = (const float*)d_in[5];
    const float* pm_b = (const float*)d_in[6];
    const float* vm_W = (const float*)d_in[7];
    const float* vm_b = (const float*)d_in[8];
    const float* Wqkv = (const float*)d_in[9];
    const float* bqkv = (const float*)d_in[10];
    const float* Wo   = (const float*)d_in[11];
    const float* bo   = (const float*)d_in[12];
    const float* ln1g = (const float*)d_in[13];
    const float* ln1b = (const float*)d_in[14];
    const float* ln2g = (const float*)d_in[15];
    const float* ln2b = (const float*)d_in[16];
    const float* W1   = (const float*)d_in[17];
    const float* b1   = (const float*)d_in[18];
    const float* W2   = (const float*)d_in[19];
    const float* b2   = (const float*)d_in[20];
    const float* out_W = (const float*)d_in[21];
    const float* out_b = (const float*)d_in[22];
    const float* crit_W = (const float*)d_in[23];
    const float* crit_b = (const float*)d_in[24];

    char* ws = (char*)d_ws;
    const size_t MB = 1024*1024;
    float* x    = (float*)(ws);                      // [8192][256] f32   :  0..8 MB
    u16*   hbuf = (u16*)(ws + 8*MB);                 // [8192][256] bf16  :  8..12
    u16*   aout = (u16*)(ws + 12*MB);                // [8192][256] bf16  : 12..16
    u16*   qkv  = (u16*)(ws + 16*MB);                // [8192][768] bf16  : 16..28
    u16*   ff1  = (u16*)(ws + 28*MB);                // [8192][1024] bf16 : 28..44
    u16*   wq   = (u16*)(ws + 44*MB);                // [3][768][256]
    u16*   wo   = wq + (size_t)3*768*256;            // [3][256][256]
    u16*   w1   = wo + (size_t)3*256*256;            // [3][1024][256]
    u16*   w2   = w1 + (size_t)3*1024*256;           // [3][256][1024]
    int*   counts  = (int*)(ws + 50*MB);             // [8][256]
    int*   offs    = counts + NB*256;
    int*   mypos   = offs   + NB*256;                // [8][1024]
    int*   members = mypos  + NB*SEQQ;               // [8][1024]

    // weight transpose-casts (f32 [K][N] -> bf16 [N][K]), once per launch
    tcast_kernel<<<dim3(768/32, 256/32, 3), 256, 0, stream>>>(Wqkv, wq, 256, 768);
    tcast_kernel<<<dim3(256/32, 256/32, 3), 256, 0, stream>>>(Wo,   wo, 256, 256);
    tcast_kernel<<<dim3(1024/32,256/32, 3), 256, 0, stream>>>(W1,   w1, 256, 1024);
    tcast_kernel<<<dim3(256/32,1024/32, 3), 256, 0, stream>>>(W2,   w2, 1024, 256);

    hipMemsetAsync(counts, 0, NB*256*sizeof(int), stream);
    group_count_kernel<<<MROWS/256, 256, 0, stream>>>(rel, mask, counts, mypos);
    group_scan_kernel<<<1, 64, 0, stream>>>(counts, offs);
    group_scatter_kernel<<<MROWS/256, 256, 0, stream>>>(rel, mask, offs, mypos, members);

    embed_kernel<<<MROWS, 256, 0, stream>>>(vm_states, num_step, pm_states,
                                            pm_W, pm_b, vm_W, vm_b, x);
    for (int i=0;i<3;i++){
        ln_kernel<<<MROWS,256,0,stream>>>(x, ln1g + i*DD, ln1b + i*DD, hbuf);
        mgemm_kernel<0><<<dim3(768/128, MROWS/128),256,0,stream>>>(
            hbuf, wq + (size_t)i*768*256, bqkv + i*768, nullptr, qkv, 768, 256);
        attn_kernel<<<MROWS/4, 256, 0, stream>>>(qkv, rel, counts, offs, members, aout);
        mgemm_kernel<1><<<dim3(256/128, MROWS/128),256,0,stream>>>(
            aout, wo + (size_t)i*256*256, bo + i*DD, x, x, 256, 256);
        ln_kernel<<<MROWS,256,0,stream>>>(x, ln2g + i*DD, ln2b + i*DD, hbuf);
        mgemm_kernel<2><<<dim3(1024/128, MROWS/128),256,0,stream>>>(
            hbuf, w1 + (size_t)i*1024*256, b1 + i*FF, nullptr, ff1, 1024, 256);
        mgemm_kernel<1><<<dim3(256/128, MROWS/128),256,0,stream>>>(
            ff1, w2 + (size_t)i*256*1024, b2 + i*DD, x, x, 256, 1024);
    }
    out_kernel<<<(NB*769+3)/4, 256, 0, stream>>>(x, out_W, out_b, crit_W, crit_b, (float*)d_out);
}